// Round 3
// baseline (5418.637 us; speedup 1.0000x reference)
//
#include <hip/hip_runtime.h>
#include <hip/hip_bf16.h>

#define B_ 64
#define T_ 512
#define D_ 1024

// d_out element offsets (FLOAT32 elements)
#define OUT0_OFF 0u         // output [B,T,D]
#define OUT1_OFF 33554432u  // masks  [B,T,1]
#define OUT2_OFF 33587200u  // gcn    [B,T,D]
#define OUT3_OFF 67141632u  // att    [B,T]

#define BM 64
#define BN 64
#define BK 16

// ---------------- pool: subj[b,d] = max_t (subj_pos==0) gcn[b,t,d] ----------------
__global__ __launch_bounds__(256) void pool_kernel(const float* __restrict__ gcn,
                                                   const int* __restrict__ subj_pos,
                                                   float* __restrict__ subj) {
    __shared__ int keep[T_];
    int b = blockIdx.y;
    int d = blockIdx.x * 256 + threadIdx.x;
    for (int t = threadIdx.x; t < T_; t += 256) keep[t] = (subj_pos[b * T_ + t] == 0);
    __syncthreads();
    const float* gb = gcn + (size_t)b * T_ * D_;
    float mx = -1e12f;
    for (int t = 0; t < T_; t++) {
        float v = gb[(size_t)t * D_ + d];
        if (keep[t]) mx = fmaxf(mx, v);
    }
    subj[b * D_ + d] = mx;
}

// ---------------- q = relu([subj,subj] @ Wq + bq) ----------------
__global__ __launch_bounds__(256) void mv_q(const float* __restrict__ subj,
                                            const float* __restrict__ Wq,
                                            const float* __restrict__ bq,
                                            float* __restrict__ q) {
    __shared__ float sv[D_];
    int b = blockIdx.y;
    int j = blockIdx.x * 256 + threadIdx.x;
    for (int i = threadIdx.x; i < D_; i += 256) sv[i] = subj[b * D_ + i];
    __syncthreads();
    float acc = bq[j];
    for (int i = 0; i < 2 * D_; i++) acc += sv[i & (D_ - 1)] * Wq[(size_t)i * D_ + j];
    q[b * D_ + j] = fmaxf(acc, 0.f);
}

// ---------------- tvec = relu([q, 0] @ Wc + bc) -> first D rows of Wc ----------------
__global__ __launch_bounds__(256) void mv_t(const float* __restrict__ q,
                                            const float* __restrict__ Wc,
                                            const float* __restrict__ bc,
                                            float* __restrict__ tv) {
    __shared__ float sv[D_];
    int b = blockIdx.y;
    int j = blockIdx.x * 256 + threadIdx.x;
    for (int i = threadIdx.x; i < D_; i += 256) sv[i] = q[b * D_ + i];
    __syncthreads();
    float acc = bc[j];
    for (int i = 0; i < D_; i++) acc += sv[i] * Wc[(size_t)i * D_ + j];
    tv[b * D_ + j] = fmaxf(acc, 0.f);
}

// ---------------- k-softmax over T, c = sum_t k[t]*gcn[b,t,:] ----------------
__global__ __launch_bounds__(256) void attk_kernel(const float* __restrict__ gcn,
                                                   const float* __restrict__ tv,
                                                   const float* __restrict__ Wk,
                                                   const float* __restrict__ bk,
                                                   float* __restrict__ cbuf) {
    __shared__ float w2[D_];
    __shared__ float lg[T_];
    __shared__ float red[4];
    int b = blockIdx.x, tid = threadIdx.x;
    int wave = tid >> 6, lane = tid & 63;
    for (int d = tid; d < D_; d += 256) w2[d] = tv[b * D_ + d] * Wk[d];
    __syncthreads();
    const float* gb = gcn + (size_t)b * T_ * D_;
    for (int t = wave; t < T_; t += 4) {
        const float* row = gb + (size_t)t * D_;
        float s = 0.f;
        for (int d = lane; d < D_; d += 64) s += w2[d] * row[d];
        #pragma unroll
        for (int off = 32; off; off >>= 1) s += __shfl_xor(s, off);
        if (lane == 0) lg[t] = s + bk[0];
    }
    __syncthreads();
    float mx = -1e30f;
    for (int t = tid; t < T_; t += 256) mx = fmaxf(mx, lg[t]);
    #pragma unroll
    for (int off = 32; off; off >>= 1) mx = fmaxf(mx, __shfl_xor(mx, off));
    if (lane == 0) red[wave] = mx;
    __syncthreads();
    mx = fmaxf(fmaxf(red[0], red[1]), fmaxf(red[2], red[3]));
    __syncthreads();
    float zs = 0.f;
    for (int t = tid; t < T_; t += 256) {
        float e = expf(lg[t] - mx);
        lg[t] = e;
        zs += e;
    }
    #pragma unroll
    for (int off = 32; off; off >>= 1) zs += __shfl_xor(zs, off);
    if (lane == 0) red[wave] = zs;
    __syncthreads();
    float invZ = 1.f / (red[0] + red[1] + red[2] + red[3]);
    for (int d0 = 0; d0 < D_; d0 += 256) {
        float acc = 0.f;
        for (int t = 0; t < T_; t++) acc += lg[t] * gb[(size_t)t * D_ + d0 + tid];
        cbuf[b * D_ + d0 + tid] = acc * invZ;
    }
}

// ---------------- m = relu([c, subj, subj] @ Wm + bm) ----------------
__global__ __launch_bounds__(256) void mv_m(const float* __restrict__ cbuf,
                                            const float* __restrict__ subj,
                                            const float* __restrict__ Wm,
                                            const float* __restrict__ bm,
                                            float* __restrict__ m) {
    __shared__ float sc[D_];
    __shared__ float ss[D_];
    int b = blockIdx.y;
    int j = blockIdx.x * 256 + threadIdx.x;
    for (int i = threadIdx.x; i < D_; i += 256) {
        sc[i] = cbuf[b * D_ + i];
        ss[i] = subj[b * D_ + i];
    }
    __syncthreads();
    float acc = bm[j];
    for (int i = 0; i < 3 * D_; i++) {
        float v = (i < D_) ? sc[i] : ss[(i - D_) & (D_ - 1)];
        acc += v * Wm[(size_t)i * D_ + j];
    }
    m[b * D_ + j] = fmaxf(acc, 0.f);
}

// ---------------- P[a,c] = sum_k WK[a,k] * WQ[c,k]  (D x D) ----------------
__global__ __launch_bounds__(256) void gemm_p(const float* __restrict__ WKm,
                                              const float* __restrict__ WQm,
                                              float* __restrict__ P) {
    __shared__ float As[BM][BK + 1];
    __shared__ float Bs[BK][BN + 1];
    int tid = threadIdx.x;
    int tx = tid & 15, ty = tid >> 4;
    int rowBase = blockIdx.x * BM;
    int colBase = blockIdx.y * BN;
    float acc[4][4] = {};
    for (int kb = 0; kb < D_; kb += BK) {
        #pragma unroll
        for (int rep = 0; rep < 4; rep++) {
            int e = tid + rep * 256;
            int r = e >> 4, c = e & 15;
            As[r][c] = WKm[(size_t)(rowBase + r) * D_ + kb + c];
        }
        #pragma unroll
        for (int rep = 0; rep < 4; rep++) {
            int e = tid + rep * 256;
            int cn = e >> 4, rk = e & 15;
            Bs[rk][cn] = WQm[(size_t)(colBase + cn) * D_ + kb + rk];
        }
        __syncthreads();
        #pragma unroll
        for (int kk = 0; kk < BK; kk++) {
            float a[4], bf[4];
            #pragma unroll
            for (int i = 0; i < 4; i++) a[i] = As[ty + i * 16][kk];
            #pragma unroll
            for (int j = 0; j < 4; j++) bf[j] = Bs[kk][tx + j * 16];
            #pragma unroll
            for (int i = 0; i < 4; i++)
                #pragma unroll
                for (int j = 0; j < 4; j++) acc[i][j] += a[i] * bf[j];
        }
        __syncthreads();
    }
    #pragma unroll
    for (int i = 0; i < 4; i++) {
        int row = rowBase + ty + i * 16;
        #pragma unroll
        for (int j = 0; j < 4; j++) {
            int col = colBase + tx + j * 16;
            P[(size_t)row * D_ + col] = acc[i][j];
        }
    }
}

// ---------------- u = WK@bQ, w = WQ@bK, alpha = bK.bQ ----------------
__global__ __launch_bounds__(256) void vecs_kernel(const float* __restrict__ WKm,
                                                   const float* __restrict__ WQm,
                                                   const float* __restrict__ bKv,
                                                   const float* __restrict__ bQv,
                                                   float* __restrict__ u,
                                                   float* __restrict__ w,
                                                   float* __restrict__ alpha) {
    int tid = threadIdx.x, wave = tid >> 6, lane = tid & 63;
    int row = blockIdx.x * 4 + wave;
    float s1 = 0.f, s2 = 0.f;
    for (int c = lane; c < D_; c += 64) {
        s1 += WKm[(size_t)row * D_ + c] * bQv[c];
        s2 += WQm[(size_t)row * D_ + c] * bKv[c];
    }
    #pragma unroll
    for (int off = 32; off; off >>= 1) {
        s1 += __shfl_xor(s1, off);
        s2 += __shfl_xor(s2, off);
    }
    if (lane == 0) { u[row] = s1; w[row] = s2; }
    if (blockIdx.x == 0 && wave == 0) {
        float a = 0.f;
        for (int c = lane; c < D_; c += 64) a += bKv[c] * bQv[c];
        #pragma unroll
        for (int off = 32; off; off >>= 1) a += __shfl_xor(a, off);
        if (lane == 0) alpha[0] = a;
    }
}

// ---------------- Gu[r] = gcn[r,:].u + alpha, Gw[r] = gcn[r,:].w ----------------
__global__ __launch_bounds__(256) void gu_kernel(const float* __restrict__ gcn,
                                                 const float* __restrict__ u,
                                                 const float* __restrict__ w,
                                                 const float* __restrict__ alpha,
                                                 float* __restrict__ Gu,
                                                 float* __restrict__ Gw) {
    int tid = threadIdx.x, wave = tid >> 6, lane = tid & 63;
    size_t row = (size_t)blockIdx.x * 4 + wave;
    const float* g = gcn + row * D_;
    float s1 = 0.f, s2 = 0.f;
    for (int c = lane; c < D_; c += 64) {
        float gv = g[c];
        s1 += gv * u[c];
        s2 += gv * w[c];
    }
    #pragma unroll
    for (int off = 32; off; off >>= 1) {
        s1 += __shfl_xor(s1, off);
        s2 += __shfl_xor(s2, off);
    }
    if (lane == 0) { Gu[row] = s1 + alpha[0]; Gw[row] = s2; }
}

// ---------------- generic f32 NN GEMM: C = A[M,K]@W[K,N], z-batched by strides ----------------
__global__ __launch_bounds__(256) void gemm_nn_f32(const float* __restrict__ A, size_t sA,
                                                   const float* __restrict__ W, size_t sW,
                                                   float* __restrict__ C, size_t sC,
                                                   int N, int K) {
    __shared__ float As[BM][BK + 1];
    __shared__ float Bs[BK][BN + 1];
    int z = blockIdx.z;
    A += (size_t)z * sA;
    W += (size_t)z * sW;
    C += (size_t)z * sC;
    int tid = threadIdx.x;
    int tx = tid & 15, ty = tid >> 4;
    size_t rowBase = (size_t)blockIdx.x * BM;
    int colBase = blockIdx.y * BN;
    float acc[4][4] = {};
    for (int kb = 0; kb < K; kb += BK) {
        #pragma unroll
        for (int rep = 0; rep < 4; rep++) {
            int e = tid + rep * 256;
            int r = e >> 4, c = e & 15;
            As[r][c] = A[(rowBase + r) * (size_t)K + kb + c];
        }
        #pragma unroll
        for (int rep = 0; rep < 4; rep++) {
            int e = tid + rep * 256;
            int r = e >> 6, c = e & 63;
            Bs[r][c] = W[(size_t)(kb + r) * N + colBase + c];
        }
        __syncthreads();
        #pragma unroll
        for (int kk = 0; kk < BK; kk++) {
            float a[4], bf[4];
            #pragma unroll
            for (int i = 0; i < 4; i++) a[i] = As[ty + i * 16][kk];
            #pragma unroll
            for (int j = 0; j < 4; j++) bf[j] = Bs[kk][tx + j * 16];
            #pragma unroll
            for (int i = 0; i < 4; i++)
                #pragma unroll
                for (int j = 0; j < 4; j++) acc[i][j] += a[i] * bf[j];
        }
        __syncthreads();
    }
    #pragma unroll
    for (int i = 0; i < 4; i++) {
        size_t row = rowBase + ty + i * 16;
        #pragma unroll
        for (int j = 0; j < 4; j++) {
            int col = colBase + tx + j * 16;
            C[row * N + col] = acc[i][j];
        }
    }
}

// ---------------- S[z,t,s] = Y[z,t,:].G[z,s,:] + Gu[z,t] + Gw[z,s] ----------------
__global__ __launch_bounds__(256) void gemm_s(const float* __restrict__ Y,
                                              const float* __restrict__ G,
                                              const float* __restrict__ Gu,
                                              const float* __restrict__ Gw,
                                              float* __restrict__ S) {
    __shared__ float As[BM][BK + 1];
    __shared__ float Bs[BK][BN + 1];
    int z = blockIdx.z;
    const float* A = Y + (size_t)z * T_ * D_;
    const float* Bt = G + (size_t)z * T_ * D_;
    float* C = S + (size_t)z * T_ * T_;
    int tid = threadIdx.x;
    int tx = tid & 15, ty = tid >> 4;
    int rowBase = blockIdx.x * BM;
    int colBase = blockIdx.y * BN;
    float acc[4][4] = {};
    for (int kb = 0; kb < D_; kb += BK) {
        #pragma unroll
        for (int rep = 0; rep < 4; rep++) {
            int e = tid + rep * 256;
            int r = e >> 4, c = e & 15;
            As[r][c] = A[(size_t)(rowBase + r) * D_ + kb + c];
        }
        #pragma unroll
        for (int rep = 0; rep < 4; rep++) {
            int e = tid + rep * 256;
            int cn = e >> 4, rk = e & 15;
            Bs[rk][cn] = Bt[(size_t)(colBase + cn) * D_ + kb + rk];
        }
        __syncthreads();
        #pragma unroll
        for (int kk = 0; kk < BK; kk++) {
            float a[4], bf[4];
            #pragma unroll
            for (int i = 0; i < 4; i++) a[i] = As[ty + i * 16][kk];
            #pragma unroll
            for (int j = 0; j < 4; j++) bf[j] = Bs[kk][tx + j * 16];
            #pragma unroll
            for (int i = 0; i < 4; i++)
                #pragma unroll
                for (int j = 0; j < 4; j++) acc[i][j] += a[i] * bf[j];
        }
        __syncthreads();
    }
    #pragma unroll
    for (int i = 0; i < 4; i++) {
        int row = rowBase + ty + i * 16;
        #pragma unroll
        for (int j = 0; j < 4; j++) {
            int col = colBase + tx + j * 16;
            C[(size_t)row * T_ + col] = acc[i][j] + Gu[z * T_ + row] + Gw[z * T_ + col];
        }
    }
}

// ---------------- per-row: att out (f32) + probs in place ----------------
__global__ __launch_bounds__(64) void softmax_att(float* __restrict__ S, float* __restrict__ att) {
    const float SCALE = 0.03125f;  // 1/sqrt(1024)
    int t = blockIdx.x, z = blockIdx.y, lane = threadIdx.x;
    float* row = S + ((size_t)z * T_ + t) * T_;
    float v[8];
    float mx = -1e30f;
    #pragma unroll
    for (int k = 0; k < 8; k++) {
        v[k] = row[lane + k * 64];
        mx = fmaxf(mx, v[k]);
    }
    #pragma unroll
    for (int off = 32; off; off >>= 1) mx = fmaxf(mx, __shfl_xor(mx, off));
    float z1 = 0.f, z2 = 0.f, dg = 0.f;
    #pragma unroll
    for (int k = 0; k < 8; k++) {
        float x = v[k] - mx;
        float e1 = expf(x);
        float e2 = expf(x * SCALE);
        z1 += e1;
        z2 += e2;
        if (lane + k * 64 == t) dg = e1;
        v[k] = e2;
    }
    #pragma unroll
    for (int off = 32; off; off >>= 1) {
        z1 += __shfl_xor(z1, off);
        z2 += __shfl_xor(z2, off);
        dg += __shfl_xor(dg, off);
    }
    float inv2 = 1.f / z2;
    #pragma unroll
    for (int k = 0; k < 8; k++) row[lane + k * 64] = v[k] * inv2;
    if (lane == 0) att[z * T_ + t] = SCALE * (1.f - dg / z1);
}

// ---------------- out0[z] = (Z[z]@WV + bV) * gate (f32) ----------------
__global__ __launch_bounds__(256) void gemm_o(const float* __restrict__ Zb,
                                              const float* __restrict__ WVm,
                                              const float* __restrict__ bVv,
                                              const float* __restrict__ gate,
                                              float* __restrict__ out) {
    __shared__ float As[BM][BK + 1];
    __shared__ float Bs[BK][BN + 1];
    int z = blockIdx.z;
    const float* A = Zb + (size_t)z * T_ * D_;
    int tid = threadIdx.x;
    int tx = tid & 15, ty = tid >> 4;
    int rowBase = blockIdx.x * BM;
    int colBase = blockIdx.y * BN;
    float acc[4][4] = {};
    for (int kb = 0; kb < D_; kb += BK) {
        #pragma unroll
        for (int rep = 0; rep < 4; rep++) {
            int e = tid + rep * 256;
            int r = e >> 4, c = e & 15;
            As[r][c] = A[(size_t)(rowBase + r) * D_ + kb + c];
        }
        #pragma unroll
        for (int rep = 0; rep < 4; rep++) {
            int e = tid + rep * 256;
            int r = e >> 6, c = e & 63;
            Bs[r][c] = WVm[(size_t)(kb + r) * D_ + colBase + c];
        }
        __syncthreads();
        #pragma unroll
        for (int kk = 0; kk < BK; kk++) {
            float a[4], bf[4];
            #pragma unroll
            for (int i = 0; i < 4; i++) a[i] = As[ty + i * 16][kk];
            #pragma unroll
            for (int j = 0; j < 4; j++) bf[j] = Bs[kk][tx + j * 16];
            #pragma unroll
            for (int i = 0; i < 4; i++)
                #pragma unroll
                for (int j = 0; j < 4; j++) acc[i][j] += a[i] * bf[j];
        }
        __syncthreads();
    }
    #pragma unroll
    for (int i = 0; i < 4; i++) {
        int row = rowBase + ty + i * 16;
        #pragma unroll
        for (int j = 0; j < 4; j++) {
            int col = colBase + tx + j * 16;
            float g = gate[z * D_ + col];
            out[((size_t)z * T_ + row) * D_ + col] = (acc[i][j] + bVv[col]) * g;
        }
    }
}

// ---------------- masks passthrough (f32) ----------------
__global__ __launch_bounds__(256) void masks_kernel(const int* __restrict__ masks,
                                                    float* __restrict__ out_masks) {
    int i = blockIdx.x * 256 + threadIdx.x;
    if (i < B_ * T_) out_masks[i] = (float)masks[i];
}

extern "C" void kernel_launch(void* const* d_in, const int* in_sizes, int n_in,
                              void* d_out, int out_size, void* d_ws, size_t ws_size,
                              hipStream_t stream) {
    const float* gcn = (const float*)d_in[0];
    const int* subj_pos = (const int*)d_in[1];
    // d_in[2] obj_pos unused (reference uses subj_mask for both pools)
    const int* masks = (const int*)d_in[3];
    const float* Wq = (const float*)d_in[4];
    const float* bq = (const float*)d_in[5];
    const float* Wc = (const float*)d_in[6];
    const float* bc = (const float*)d_in[7];
    const float* Wk = (const float*)d_in[8];
    const float* bk = (const float*)d_in[9];
    const float* Wm = (const float*)d_in[10];
    const float* bm = (const float*)d_in[11];
    const float* WK = (const float*)d_in[12];
    const float* bK = (const float*)d_in[13];
    const float* WQ = (const float*)d_in[14];
    const float* bQ = (const float*)d_in[15];
    const float* WV = (const float*)d_in[16];
    const float* bV = (const float*)d_in[17];

    float* out = (float*)d_out;

    // ---- workspace layout (floats), small buffers FIRST ----
    float* ws = (float*)d_ws;
    float* subj = ws;                   // B*D
    float* qv   = subj + B_ * D_;       // B*D
    float* tv   = qv + B_ * D_;         // B*D
    float* cb   = tv + B_ * D_;         // B*D
    float* mb   = cb + B_ * D_;         // B*D
    float* u    = mb + B_ * D_;         // D
    float* w    = u + D_;               // D
    float* alph = w + D_;               // D (slot, 1 used)
    float* Gu   = alph + D_;            // B*T
    float* Gw   = Gu + B_ * T_;         // B*T
    float* P    = Gw + B_ * T_;         // D*D
    float* Y    = P + (size_t)D_ * D_;  // nc*T*D
    // S follows Y, depends on nc

    const size_t smallFloats = (size_t)(5 * B_ * D_ + 3 * D_ + 2 * B_ * T_) + (size_t)D_ * D_;
    int nc = 64;
    while (nc > 1) {
        size_t need = (smallFloats + (size_t)nc * T_ * (D_ + T_)) * sizeof(float);
        if (need <= ws_size) break;
        nc >>= 1;
    }
    float* S = Y + (size_t)nc * T_ * D_;  // nc*T*T

    // ---- small path: m gate and pooled vectors ----
    pool_kernel<<<dim3(D_ / 256, B_), 256, 0, stream>>>(gcn, subj_pos, subj);
    mv_q<<<dim3(D_ / 256, B_), 256, 0, stream>>>(subj, Wq, bq, qv);
    mv_t<<<dim3(D_ / 256, B_), 256, 0, stream>>>(qv, Wc, bc, tv);
    attk_kernel<<<B_, 256, 0, stream>>>(gcn, tv, Wk, bk, cb);
    mv_m<<<dim3(D_ / 256, B_), 256, 0, stream>>>(cb, subj, Wm, bm, mb);

    // ---- score factorization precompute ----
    gemm_p<<<dim3(D_ / BM, D_ / BN), 256, 0, stream>>>(WK, WQ, P);
    vecs_kernel<<<D_ / 4, 256, 0, stream>>>(WK, WQ, bK, bQ, u, w, alph);
    gu_kernel<<<B_ * T_ / 4, 256, 0, stream>>>(gcn, u, w, alph, Gu, Gw);

    // ---- chunked attention: Y=G@P, S=Y@G^T(+Gu,Gw), softmax, Z=probs@G (into Y), out0=(Z@WV+bV)*m ----
    for (int b0 = 0; b0 < B_; b0 += nc) {
        const float* Gc = gcn + (size_t)b0 * T_ * D_;
        gemm_nn_f32<<<dim3(nc * T_ / BM, D_ / BN, 1), 256, 0, stream>>>(
            Gc, 0, P, 0, Y, 0, D_, D_);
        gemm_s<<<dim3(T_ / BM, T_ / BN, nc), 256, 0, stream>>>(
            Y, Gc, Gu + (size_t)b0 * T_, Gw + (size_t)b0 * T_, S);
        softmax_att<<<dim3(T_, nc), 64, 0, stream>>>(S, out + OUT3_OFF + (size_t)b0 * T_);
        gemm_nn_f32<<<dim3(T_ / BM, D_ / BN, nc), 256, 0, stream>>>(
            S, (size_t)T_ * T_, Gc, (size_t)T_ * D_, Y, (size_t)T_ * D_, D_, T_);
        gemm_o<<<dim3(T_ / BM, D_ / BN, nc), 256, 0, stream>>>(
            Y, WV, bV, mb + (size_t)b0 * D_, out + OUT0_OFF + (size_t)b0 * T_ * D_);
    }

    // ---- passthroughs: gcn (f32 D2D copy) + masks ----
    hipMemcpyAsync(out + OUT2_OFF, gcn, (size_t)B_ * T_ * D_ * sizeof(float),
                   hipMemcpyDeviceToDevice, stream);
    masks_kernel<<<(B_ * T_ + 255) / 256, 256, 0, stream>>>(masks, out + OUT1_OFF);
}

// Round 4
// 2014.408 us; speedup vs baseline: 2.6899x; 2.6899x over previous
//
#include <hip/hip_runtime.h>
#include <hip/hip_bf16.h>

#define B_ 64
#define T_ 512
#define D_ 1024

// d_out element offsets (FLOAT32 elements)
#define OUT0_OFF 0u         // output [B,T,D]
#define OUT1_OFF 33554432u  // masks  [B,T,1]
#define OUT2_OFF 33587200u  // gcn    [B,T,D]
#define OUT3_OFF 67141632u  // att    [B,T]

typedef __attribute__((ext_vector_type(8))) short short8;
typedef __attribute__((ext_vector_type(2))) short short2v;
typedef __attribute__((ext_vector_type(4))) float f32x4;

__device__ __forceinline__ short bf16_of(float x) {
    __hip_bfloat16 h = __float2bfloat16(x);
    return *reinterpret_cast<short*>(&h);
}
__device__ __forceinline__ float f32_of(short s) {
    __hip_bfloat16 h;
    *reinterpret_cast<short*>(&h) = s;
    return __bfloat162float(h);
}

// ---------------- pool: subj[b,d] = max_t (subj_pos==0) gcn[b,t,d] ----------------
__global__ __launch_bounds__(256) void pool_kernel(const float* __restrict__ gcn,
                                                   const int* __restrict__ subj_pos,
                                                   float* __restrict__ subj) {
    __shared__ int keep[T_];
    int b = blockIdx.y;
    int d = blockIdx.x * 256 + threadIdx.x;
    for (int t = threadIdx.x; t < T_; t += 256) keep[t] = (subj_pos[b * T_ + t] == 0);
    __syncthreads();
    const float* gb = gcn + (size_t)b * T_ * D_;
    float mx = -1e12f;
    for (int t = 0; t < T_; t++) {
        float v = gb[(size_t)t * D_ + d];
        if (keep[t]) mx = fmaxf(mx, v);
    }
    subj[b * D_ + d] = mx;
}

// ---------------- q = relu([subj,subj] @ Wq + bq) ----------------
__global__ __launch_bounds__(256) void mv_q(const float* __restrict__ subj,
                                            const float* __restrict__ Wq,
                                            const float* __restrict__ bq,
                                            float* __restrict__ q) {
    __shared__ float sv[D_];
    int b = blockIdx.y;
    int j = blockIdx.x * 256 + threadIdx.x;
    for (int i = threadIdx.x; i < D_; i += 256) sv[i] = subj[b * D_ + i];
    __syncthreads();
    float acc = bq[j];
    for (int i = 0; i < 2 * D_; i++) acc += sv[i & (D_ - 1)] * Wq[(size_t)i * D_ + j];
    q[b * D_ + j] = fmaxf(acc, 0.f);
}

// ---------------- tvec = relu([q, 0] @ Wc + bc) ----------------
__global__ __launch_bounds__(256) void mv_t(const float* __restrict__ q,
                                            const float* __restrict__ Wc,
                                            const float* __restrict__ bc,
                                            float* __restrict__ tv) {
    __shared__ float sv[D_];
    int b = blockIdx.y;
    int j = blockIdx.x * 256 + threadIdx.x;
    for (int i = threadIdx.x; i < D_; i += 256) sv[i] = q[b * D_ + i];
    __syncthreads();
    float acc = bc[j];
    for (int i = 0; i < D_; i++) acc += sv[i] * Wc[(size_t)i * D_ + j];
    tv[b * D_ + j] = fmaxf(acc, 0.f);
}

// ---------------- k-softmax over T, c = sum_t k[t]*gcn[b,t,:] ----------------
__global__ __launch_bounds__(256) void attk_kernel(const float* __restrict__ gcn,
                                                   const float* __restrict__ tv,
                                                   const float* __restrict__ Wk,
                                                   const float* __restrict__ bk,
                                                   float* __restrict__ cbuf) {
    __shared__ float w2[D_];
    __shared__ float lg[T_];
    __shared__ float red[4];
    int b = blockIdx.x, tid = threadIdx.x;
    int wave = tid >> 6, lane = tid & 63;
    for (int d = tid; d < D_; d += 256) w2[d] = tv[b * D_ + d] * Wk[d];
    __syncthreads();
    const float* gb = gcn + (size_t)b * T_ * D_;
    for (int t = wave; t < T_; t += 4) {
        const float* row = gb + (size_t)t * D_;
        float s = 0.f;
        for (int d = lane; d < D_; d += 64) s += w2[d] * row[d];
        #pragma unroll
        for (int off = 32; off; off >>= 1) s += __shfl_xor(s, off);
        if (lane == 0) lg[t] = s + bk[0];
    }
    __syncthreads();
    float mx = -1e30f;
    for (int t = tid; t < T_; t += 256) mx = fmaxf(mx, lg[t]);
    #pragma unroll
    for (int off = 32; off; off >>= 1) mx = fmaxf(mx, __shfl_xor(mx, off));
    if (lane == 0) red[wave] = mx;
    __syncthreads();
    mx = fmaxf(fmaxf(red[0], red[1]), fmaxf(red[2], red[3]));
    __syncthreads();
    float zs = 0.f;
    for (int t = tid; t < T_; t += 256) {
        float e = expf(lg[t] - mx);
        lg[t] = e;
        zs += e;
    }
    #pragma unroll
    for (int off = 32; off; off >>= 1) zs += __shfl_xor(zs, off);
    if (lane == 0) red[wave] = zs;
    __syncthreads();
    float invZ = 1.f / (red[0] + red[1] + red[2] + red[3]);
    for (int d0 = 0; d0 < D_; d0 += 256) {
        float acc = 0.f;
        for (int t = 0; t < T_; t++) acc += lg[t] * gb[(size_t)t * D_ + d0 + tid];
        cbuf[b * D_ + d0 + tid] = acc * invZ;
    }
}

// ---------------- m = relu([c, subj, subj] @ Wm + bm) ----------------
__global__ __launch_bounds__(256) void mv_m(const float* __restrict__ cbuf,
                                            const float* __restrict__ subj,
                                            const float* __restrict__ Wm,
                                            const float* __restrict__ bm,
                                            float* __restrict__ m) {
    __shared__ float sc[D_];
    __shared__ float ss[D_];
    int b = blockIdx.y;
    int j = blockIdx.x * 256 + threadIdx.x;
    for (int i = threadIdx.x; i < D_; i += 256) {
        sc[i] = cbuf[b * D_ + i];
        ss[i] = subj[b * D_ + i];
    }
    __syncthreads();
    float acc = bm[j];
    for (int i = 0; i < 3 * D_; i++) {
        float v = (i < D_) ? sc[i] : ss[(i - D_) & (D_ - 1)];
        acc += v * Wm[(size_t)i * D_ + j];
    }
    m[b * D_ + j] = fmaxf(acc, 0.f);
}

// ---------------- u = WK@bQ, w = WQ@bK, alpha = bK.bQ ----------------
__global__ __launch_bounds__(256) void vecs_kernel(const float* __restrict__ WKm,
                                                   const float* __restrict__ WQm,
                                                   const float* __restrict__ bKv,
                                                   const float* __restrict__ bQv,
                                                   float* __restrict__ u,
                                                   float* __restrict__ w,
                                                   float* __restrict__ alpha) {
    int tid = threadIdx.x, wave = tid >> 6, lane = tid & 63;
    int row = blockIdx.x * 4 + wave;
    float s1 = 0.f, s2 = 0.f;
    for (int c = lane; c < D_; c += 64) {
        s1 += WKm[(size_t)row * D_ + c] * bQv[c];
        s2 += WQm[(size_t)row * D_ + c] * bKv[c];
    }
    #pragma unroll
    for (int off = 32; off; off >>= 1) {
        s1 += __shfl_xor(s1, off);
        s2 += __shfl_xor(s2, off);
    }
    if (lane == 0) { u[row] = s1; w[row] = s2; }
    if (blockIdx.x == 0 && wave == 0) {
        float a = 0.f;
        for (int c = lane; c < D_; c += 64) a += bKv[c] * bQv[c];
        #pragma unroll
        for (int off = 32; off; off >>= 1) a += __shfl_xor(a, off);
        if (lane == 0) alpha[0] = a;
    }
}

// ---------------- Gu[r] = gcn[r,:].u + alpha, Gw[r] = gcn[r,:].w ----------------
__global__ __launch_bounds__(256) void gu_kernel(const float* __restrict__ gcn,
                                                 const float* __restrict__ u,
                                                 const float* __restrict__ w,
                                                 const float* __restrict__ alpha,
                                                 float* __restrict__ Gu,
                                                 float* __restrict__ Gw) {
    int tid = threadIdx.x, wave = tid >> 6, lane = tid & 63;
    size_t row = (size_t)blockIdx.x * 4 + wave;
    const float* g = gcn + row * D_;
    float s1 = 0.f, s2 = 0.f;
    for (int c = lane; c < D_; c += 64) {
        float gv = g[c];
        s1 += gv * u[c];
        s2 += gv * w[c];
    }
    #pragma unroll
    for (int off = 32; off; off >>= 1) {
        s1 += __shfl_xor(s1, off);
        s2 += __shfl_xor(s2, off);
    }
    if (lane == 0) { Gu[row] = s1 + alpha[0]; Gw[row] = s2; }
}

// ---------------- split f32 -> hi/lo bf16 interleaved along last dim ----------------
__global__ __launch_bounds__(256) void split_kernel(const float* __restrict__ in,
                                                    short* __restrict__ out, size_t n4) {
    size_t i = (size_t)blockIdx.x * 256 + threadIdx.x;
    size_t stride = (size_t)gridDim.x * 256;
    for (; i < n4; i += stride) {
        f32x4 v = ((const f32x4*)in)[i];
        short8 o;
        #pragma unroll
        for (int j = 0; j < 4; j++) {
            short hi = bf16_of(v[j]);
            float r = v[j] - f32_of(hi);
            o[2 * j] = hi;
            o[2 * j + 1] = bf16_of(r);
        }
        ((short8*)out)[i] = o;
    }
}

// ---------------- out[z][c][r] = bf16(in[z][r][c]) ; R,C multiples of 32 ----------------
__global__ __launch_bounds__(256) void transpose_kernel(const float* __restrict__ in, size_t sIn,
                                                        short* __restrict__ out, size_t sOut,
                                                        int R, int C) {
    __shared__ float tile[32][33];
    int z = blockIdx.z;
    in += (size_t)z * sIn;
    out += (size_t)z * sOut;
    int c0 = blockIdx.x * 32, r0 = blockIdx.y * 32;
    int tx = threadIdx.x & 31, ty = threadIdx.x >> 5;
    #pragma unroll
    for (int i = 0; i < 4; i++) {
        int r = ty + i * 8;
        tile[r][tx] = in[(size_t)(r0 + r) * C + c0 + tx];
    }
    __syncthreads();
    #pragma unroll
    for (int i = 0; i < 4; i++) {
        int c = ty + i * 8;
        out[(size_t)(c0 + c) * R + r0 + tx] = bf16_of(tile[tx][c]);
    }
}

// ================= MFMA NT bf16 GEMM: C[m,n] = sum_k A[m,k]*Bt[n,k] =================
// 128x128 tile, 4 waves (2x2 of 64x64), 16x16x32 bf16 MFMA, f32 accum.
// MODE 0: f32 store | 1: f32 + Gu[row]+Gw[col] | 2: bf16 store
// MODE 3: f32 (acc+bV[col])*gate[z*D+col]      | 4: hi/lo split bf16 store (ldout=2N)
template <int MODE>
__global__ __launch_bounds__(256) void gemm_nt(
        const short* __restrict__ A, size_t sAz,
        const short* __restrict__ Bt, size_t sBz,
        int K, int ldout,
        float* __restrict__ Cf, short* __restrict__ Cb, size_t sCz,
        const float* __restrict__ e1, const float* __restrict__ e2) {
    __shared__ __align__(16) short As[128][72];
    __shared__ __align__(16) short Bs[128][72];
    int z = blockIdx.z;
    A += (size_t)z * sAz;
    Bt += (size_t)z * sBz;
    int t = threadIdx.x;
    int lane = t & 63, wave = t >> 6;
    int wr = wave >> 1, wc = wave & 1;
    size_t rowBase = (size_t)blockIdx.x * 128;
    size_t colBase = (size_t)blockIdx.y * 128;
    f32x4 acc[4][4] = {};
    int lrow = t >> 3;          // 0..31
    int lcol = (t & 7) * 8;     // 0..56
    for (int kb = 0; kb < K; kb += 64) {
        #pragma unroll
        for (int p = 0; p < 4; p++) {
            int r = p * 32 + lrow;
            *(short8*)(&As[r][lcol]) = *(const short8*)(&A[(rowBase + r) * (size_t)K + kb + lcol]);
            *(short8*)(&Bs[r][lcol]) = *(const short8*)(&Bt[(colBase + r) * (size_t)K + kb + lcol]);
        }
        __syncthreads();
        #pragma unroll
        for (int kk = 0; kk < 64; kk += 32) {
            int ko = kk + (lane >> 4) * 8;
            short8 af[4], bfr[4];
            #pragma unroll
            for (int i = 0; i < 4; i++)
                af[i] = *(const short8*)(&As[wr * 64 + i * 16 + (lane & 15)][ko]);
            #pragma unroll
            for (int j = 0; j < 4; j++)
                bfr[j] = *(const short8*)(&Bs[wc * 64 + j * 16 + (lane & 15)][ko]);
            #pragma unroll
            for (int i = 0; i < 4; i++)
                #pragma unroll
                for (int j = 0; j < 4; j++)
                    acc[i][j] = __builtin_amdgcn_mfma_f32_16x16x32_bf16(af[i], bfr[j], acc[i][j], 0, 0, 0);
        }
        __syncthreads();
    }
    #pragma unroll
    for (int i = 0; i < 4; i++) {
        #pragma unroll
        for (int j = 0; j < 4; j++) {
            #pragma unroll
            for (int r = 0; r < 4; r++) {
                size_t row = rowBase + wr * 64 + i * 16 + (lane >> 4) * 4 + r;
                size_t col = colBase + wc * 64 + j * 16 + (lane & 15);
                float v = acc[i][j][r];
                if (MODE == 0) {
                    Cf[z * sCz + row * ldout + col] = v;
                } else if (MODE == 1) {
                    Cf[z * sCz + row * ldout + col] = v + e1[z * T_ + row] + e2[z * T_ + col];
                } else if (MODE == 2) {
                    Cb[z * sCz + row * ldout + col] = bf16_of(v);
                } else if (MODE == 3) {
                    Cf[z * sCz + row * ldout + col] = (v + e1[col]) * e2[(size_t)z * D_ + col];
                } else {
                    short hi = bf16_of(v);
                    float rr = v - f32_of(hi);
                    short2v o;
                    o[0] = hi;
                    o[1] = bf16_of(rr);
                    *(short2v*)(&Cb[row * (size_t)ldout + 2 * col]) = o;
                }
            }
        }
    }
}

// ---------------- per-row: att out (f32) + probs out (bf16) ----------------
__global__ __launch_bounds__(64) void softmax_att(const float* __restrict__ S,
                                                  short* __restrict__ probs,
                                                  float* __restrict__ att) {
    const float SCALE = 0.03125f;  // 1/sqrt(1024)
    int t = blockIdx.x, z = blockIdx.y, lane = threadIdx.x;
    const float* row = S + ((size_t)z * T_ + t) * T_;
    short* prow = probs + ((size_t)z * T_ + t) * T_;
    float v[8];
    float mx = -1e30f;
    #pragma unroll
    for (int k = 0; k < 8; k++) {
        v[k] = row[lane + k * 64];
        mx = fmaxf(mx, v[k]);
    }
    #pragma unroll
    for (int off = 32; off; off >>= 1) mx = fmaxf(mx, __shfl_xor(mx, off));
    float z1 = 0.f, z2 = 0.f, dg = 0.f;
    #pragma unroll
    for (int k = 0; k < 8; k++) {
        float x = v[k] - mx;
        float e1 = expf(x);
        float e2 = expf(x * SCALE);
        z1 += e1;
        z2 += e2;
        if (lane + k * 64 == t) dg = e1;
        v[k] = e2;
    }
    #pragma unroll
    for (int off = 32; off; off >>= 1) {
        z1 += __shfl_xor(z1, off);
        z2 += __shfl_xor(z2, off);
        dg += __shfl_xor(dg, off);
    }
    float inv2 = 1.f / z2;
    #pragma unroll
    for (int k = 0; k < 8; k++) prow[lane + k * 64] = bf16_of(v[k] * inv2);
    if (lane == 0) att[z * T_ + t] = SCALE * (1.f - dg / z1);
}

// ---------------- masks passthrough (f32) ----------------
__global__ __launch_bounds__(256) void masks_kernel(const int* __restrict__ masks,
                                                    float* __restrict__ out_masks) {
    int i = blockIdx.x * 256 + threadIdx.x;
    if (i < B_ * T_) out_masks[i] = (float)masks[i];
}

extern "C" void kernel_launch(void* const* d_in, const int* in_sizes, int n_in,
                              void* d_out, int out_size, void* d_ws, size_t ws_size,
                              hipStream_t stream) {
    const float* gcn = (const float*)d_in[0];
    const int* subj_pos = (const int*)d_in[1];
    const int* masks = (const int*)d_in[3];
    const float* Wq = (const float*)d_in[4];
    const float* bq = (const float*)d_in[5];
    const float* Wc = (const float*)d_in[6];
    const float* bc = (const float*)d_in[7];
    const float* Wk = (const float*)d_in[8];
    const float* bk = (const float*)d_in[9];
    const float* Wm = (const float*)d_in[10];
    const float* bm = (const float*)d_in[11];
    const float* WK = (const float*)d_in[12];
    const float* bK = (const float*)d_in[13];
    const float* WQ = (const float*)d_in[14];
    const float* bQ = (const float*)d_in[15];
    const float* WV = (const float*)d_in[16];
    const float* bV = (const float*)d_in[17];

    float* out = (float*)d_out;

    // ---- workspace layout (bytes, 256-aligned chunks) ----
    char* p = (char*)d_ws;
    auto alloc = [&](size_t bytes) {
        char* r = p;
        p += (bytes + 255) & ~(size_t)255;
        return r;
    };
    float* subj = (float*)alloc(B_ * D_ * 4);
    float* qv   = (float*)alloc(B_ * D_ * 4);
    float* tv   = (float*)alloc(B_ * D_ * 4);
    float* cb   = (float*)alloc(B_ * D_ * 4);
    float* mb   = (float*)alloc(B_ * D_ * 4);
    float* u    = (float*)alloc(D_ * 4);
    float* w    = (float*)alloc(D_ * 4);
    float* alph = (float*)alloc(256);
    float* Gu   = (float*)alloc(B_ * T_ * 4);
    float* Gw   = (float*)alloc(B_ * T_ * 4);
    float* Pt   = (float*)alloc((size_t)D_ * D_ * 4);
    short* WKs  = (short*)alloc((size_t)D_ * 2 * D_ * 2);
    short* WQs  = (short*)alloc((size_t)D_ * 2 * D_ * 2);
    short* Pts  = (short*)alloc((size_t)D_ * 2 * D_ * 2);
    short* WVt  = (short*)alloc((size_t)D_ * D_ * 2);

    size_t fixedBytes = (size_t)(p - (char*)d_ws);
    // per-chunk bytes (nc batches): Gs + Ys + Gt + S + probs + Zs
    const size_t perBatch = (size_t)T_ * 2 * D_ * 2   // Gs
                          + (size_t)T_ * 2 * D_ * 2   // Ys
                          + (size_t)D_ * T_ * 2       // Gt
                          + (size_t)T_ * T_ * 4       // S
                          + (size_t)T_ * T_ * 2       // probs
                          + (size_t)T_ * D_ * 2;      // Zs
    int nc = 64;
    while (nc > 1 && fixedBytes + (size_t)nc * perBatch + 4096 > ws_size) nc >>= 1;

    short* Gs_c    = (short*)alloc((size_t)nc * T_ * 2 * D_ * 2);
    short* Ys_c    = (short*)alloc((size_t)nc * T_ * 2 * D_ * 2);
    short* Gt_c    = (short*)alloc((size_t)nc * D_ * T_ * 2);
    float* S_c     = (float*)alloc((size_t)nc * T_ * T_ * 4);
    short* probs_c = (short*)alloc((size_t)nc * T_ * T_ * 2);
    short* Zs_c    = (short*)alloc((size_t)nc * T_ * D_ * 2);

    // ---- small path: gate m and pooled vectors ----
    pool_kernel<<<dim3(D_ / 256, B_), 256, 0, stream>>>(gcn, subj_pos, subj);
    mv_q<<<dim3(D_ / 256, B_), 256, 0, stream>>>(subj, Wq, bq, qv);
    mv_t<<<dim3(D_ / 256, B_), 256, 0, stream>>>(qv, Wc, bc, tv);
    attk_kernel<<<B_, 256, 0, stream>>>(gcn, tv, Wk, bk, cb);
    mv_m<<<dim3(D_ / 256, B_), 256, 0, stream>>>(cb, subj, Wm, bm, mb);

    // ---- factorization precompute (split precision) ----
    split_kernel<<<1024, 256, 0, stream>>>(WK, WKs, (size_t)D_ * D_ / 4);
    split_kernel<<<1024, 256, 0, stream>>>(WQ, WQs, (size_t)D_ * D_ / 4);
    // Pt[c,a] = sum_k WQ[c,k]*WK[a,k]  (= P[a,c])
    gemm_nt<0><<<dim3(8, 8, 1), 256, 0, stream>>>(WQs, 0, WKs, 0, 2 * D_, D_,
                                                  Pt, nullptr, 0, nullptr, nullptr);
    split_kernel<<<1024, 256, 0, stream>>>(Pt, Pts, (size_t)D_ * D_ / 4);
    // WVt[d,k] = WV[k,d]
    transpose_kernel<<<dim3(32, 32, 1), 256, 0, stream>>>(WV, 0, WVt, 0, D_, D_);
    vecs_kernel<<<D_ / 4, 256, 0, stream>>>(WK, WQ, bK, bQ, u, w, alph);
    gu_kernel<<<B_ * T_ / 4, 256, 0, stream>>>(gcn, u, w, alph, Gu, Gw);

    // ---- chunked attention ----
    for (int b0 = 0; b0 < B_; b0 += nc) {
        const float* Gc = gcn + (size_t)b0 * T_ * D_;
        // Gs = split(G), Gt = bf16(G^T)
        split_kernel<<<2048, 256, 0, stream>>>(Gc, Gs_c, (size_t)nc * T_ * D_ / 4);
        transpose_kernel<<<dim3(D_ / 32, T_ / 32, nc), 256, 0, stream>>>(
            Gc, (size_t)T_ * D_, Gt_c, (size_t)D_ * T_, T_, D_);
        // Y = G@P (split in, split-store out): A=Gs [nc*T, 2D], Bt=Pts [D, 2D]
        gemm_nt<4><<<dim3(nc * T_ / 128, D_ / 128, 1), 256, 0, stream>>>(
            Gs_c, 0, Pts, 0, 2 * D_, 2 * D_, nullptr, Ys_c, 0, nullptr, nullptr);
        // S = Y@G^T + Gu + Gw : A=Ys(z), Bt=Gs(z), K=2D
        gemm_nt<1><<<dim3(T_ / 128, T_ / 128, nc), 256, 0, stream>>>(
            Ys_c, (size_t)T_ * 2 * D_, Gs_c, (size_t)T_ * 2 * D_, 2 * D_, T_,
            S_c, nullptr, (size_t)T_ * T_, Gu + (size_t)b0 * T_, Gw + (size_t)b0 * T_);
        // softmax: att (f32) + probs (bf16)
        softmax_att<<<dim3(T_, nc), 64, 0, stream>>>(S_c, probs_c, out + OUT3_OFF + (size_t)b0 * T_);
        // Z = probs@G : A=probs(z) [T,T], Bt=Gt(z) [D,T], K=T -> bf16
        gemm_nt<2><<<dim3(T_ / 128, D_ / 128, nc), 256, 0, stream>>>(
            probs_c, (size_t)T_ * T_, Gt_c, (size_t)D_ * T_, T_, D_,
            nullptr, Zs_c, (size_t)T_ * D_, nullptr, nullptr);
        // out0 = (Z@WV + bV) * m : A=Zs(z) [T,D], Bt=WVt [D,D], K=D
        gemm_nt<3><<<dim3(T_ / 128, D_ / 128, nc), 256, 0, stream>>>(
            Zs_c, (size_t)T_ * D_, WVt, 0, D_, D_,
            out + OUT0_OFF + (size_t)b0 * T_ * D_, nullptr, (size_t)T_ * D_,
            bV, mb + (size_t)b0 * D_);
    }

    // ---- passthroughs ----
    hipMemcpyAsync(out + OUT2_OFF, gcn, (size_t)B_ * T_ * D_ * sizeof(float),
                   hipMemcpyDeviceToDevice, stream);
    masks_kernel<<<(B_ * T_ + 255) / 256, 256, 0, stream>>>(masks, out + OUT1_OFF);
}

// Round 5
// 1083.707 us; speedup vs baseline: 5.0001x; 1.8588x over previous
//
#include <hip/hip_runtime.h>
#include <hip/hip_bf16.h>

#define B_ 64
#define T_ 512
#define D_ 1024
#define NCH 8   // t-chunks for c-reduction
#define TCH 64  // T_/NCH

// d_out element offsets (FLOAT32 elements)
#define OUT0_OFF 0u         // output [B,T,D]
#define OUT1_OFF 33554432u  // masks  [B,T,1]
#define OUT2_OFF 33587200u  // gcn    [B,T,D]
#define OUT3_OFF 67141632u  // att    [B,T]

typedef __attribute__((ext_vector_type(8))) short short8;
typedef __attribute__((ext_vector_type(2))) short short2v;
typedef __attribute__((ext_vector_type(4))) float f32x4;

__device__ __forceinline__ short bf16_of(float x) {
    __hip_bfloat16 h = __float2bfloat16(x);
    return *reinterpret_cast<short*>(&h);
}
__device__ __forceinline__ float f32_of(short s) {
    __hip_bfloat16 h;
    *reinterpret_cast<short*>(&h) = s;
    return __bfloat162float(h);
}

// ---------------- pool: subj[b,d] = max_t (subj_pos==0) gcn[b,t,d] ----------------
__global__ __launch_bounds__(256) void pool_kernel(const float* __restrict__ gcn,
                                                   const int* __restrict__ subj_pos,
                                                   float* __restrict__ subj) {
    __shared__ int keep[T_];
    int b = blockIdx.y;
    int d = blockIdx.x * 256 + threadIdx.x;
    for (int t = threadIdx.x; t < T_; t += 256) keep[t] = (subj_pos[b * T_ + t] == 0);
    __syncthreads();
    const float* gb = gcn + (size_t)b * T_ * D_;
    float mx = -1e12f;
    for (int t = 0; t < T_; t++) {
        float v = gb[(size_t)t * D_ + d];
        if (keep[t]) mx = fmaxf(mx, v);
    }
    subj[b * D_ + d] = mx;
}

// ---------------- q = relu([subj,subj] @ Wq + bq) ----------------
__global__ __launch_bounds__(256) void mv_q(const float* __restrict__ subj,
                                            const float* __restrict__ Wq,
                                            const float* __restrict__ bq,
                                            float* __restrict__ q) {
    __shared__ float sv[D_];
    int b = blockIdx.y;
    int j = blockIdx.x * 256 + threadIdx.x;
    for (int i = threadIdx.x; i < D_; i += 256) sv[i] = subj[b * D_ + i];
    __syncthreads();
    float acc = bq[j];
    for (int i = 0; i < 2 * D_; i++) acc += sv[i & (D_ - 1)] * Wq[(size_t)i * D_ + j];
    q[b * D_ + j] = fmaxf(acc, 0.f);
}

// ---------------- tvec = relu([q, 0] @ Wc + bc) ----------------
__global__ __launch_bounds__(256) void mv_t(const float* __restrict__ q,
                                            const float* __restrict__ Wc,
                                            const float* __restrict__ bc,
                                            float* __restrict__ tv) {
    __shared__ float sv[D_];
    int b = blockIdx.y;
    int j = blockIdx.x * 256 + threadIdx.x;
    for (int i = threadIdx.x; i < D_; i += 256) sv[i] = q[b * D_ + i];
    __syncthreads();
    float acc = bc[j];
    for (int i = 0; i < D_; i++) acc += sv[i] * Wc[(size_t)i * D_ + j];
    tv[b * D_ + j] = fmaxf(acc, 0.f);
}

// ---------------- m = relu([c, subj, subj] @ Wm + bm) ----------------
__global__ __launch_bounds__(256) void mv_m(const float* __restrict__ cbuf,
                                            const float* __restrict__ subj,
                                            const float* __restrict__ Wm,
                                            const float* __restrict__ bm,
                                            float* __restrict__ m) {
    __shared__ float sc[D_];
    __shared__ float ss[D_];
    int b = blockIdx.y;
    int j = blockIdx.x * 256 + threadIdx.x;
    for (int i = threadIdx.x; i < D_; i += 256) {
        sc[i] = cbuf[b * D_ + i];
        ss[i] = subj[b * D_ + i];
    }
    __syncthreads();
    float acc = bm[j];
    for (int i = 0; i < 3 * D_; i++) {
        float v = (i < D_) ? sc[i] : ss[(i - D_) & (D_ - 1)];
        acc += v * Wm[(size_t)i * D_ + j];
    }
    m[b * D_ + j] = fmaxf(acc, 0.f);
}

// ---------------- u = WK@bQ, w = WQ@bK, alpha = bK.bQ ----------------
__global__ __launch_bounds__(256) void vecs_kernel(const float* __restrict__ WKm,
                                                   const float* __restrict__ WQm,
                                                   const float* __restrict__ bKv,
                                                   const float* __restrict__ bQv,
                                                   float* __restrict__ u,
                                                   float* __restrict__ w,
                                                   float* __restrict__ alpha) {
    int tid = threadIdx.x, wave = tid >> 6, lane = tid & 63;
    int row = blockIdx.x * 4 + wave;
    float s1 = 0.f, s2 = 0.f;
    for (int c = lane; c < D_; c += 64) {
        s1 += WKm[(size_t)row * D_ + c] * bQv[c];
        s2 += WQm[(size_t)row * D_ + c] * bKv[c];
    }
    #pragma unroll
    for (int off = 32; off; off >>= 1) {
        s1 += __shfl_xor(s1, off);
        s2 += __shfl_xor(s2, off);
    }
    if (lane == 0) { u[row] = s1; w[row] = s2; }
    if (blockIdx.x == 0 && wave == 0) {
        float a = 0.f;
        for (int c = lane; c < D_; c += 64) a += bKv[c] * bQv[c];
        #pragma unroll
        for (int off = 32; off; off >>= 1) a += __shfl_xor(a, off);
        if (lane == 0) alpha[0] = a;
    }
}

// ---- fused row dots: Gu[r]=g.u+alpha, Gw[r]=g.w, lg[r]=g.(tv[b]*Wk)+bk  (1 wave/row) ----
__global__ __launch_bounds__(256) void att_dots(const float* __restrict__ gcn,
                                                const float* __restrict__ u,
                                                const float* __restrict__ w,
                                                const float* __restrict__ tv,
                                                const float* __restrict__ Wk,
                                                const float* __restrict__ alpha,
                                                const float* __restrict__ bk,
                                                float* __restrict__ Gu,
                                                float* __restrict__ Gw,
                                                float* __restrict__ lg) {
    __shared__ float su[D_], sw[D_], s2[D_];
    int tid = threadIdx.x, wave = tid >> 6, lane = tid & 63;
    size_t row0 = (size_t)blockIdx.x * 4;
    int b = (int)(row0 >> 9);  // 4 rows per block share b (512 rows per b)
    for (int c = tid; c < D_; c += 256) {
        su[c] = u[c];
        sw[c] = w[c];
        s2[c] = tv[(size_t)b * D_ + c] * Wk[c];
    }
    __syncthreads();
    size_t row = row0 + wave;
    const float* g = gcn + row * D_;
    float d1 = 0.f, d2 = 0.f, d3 = 0.f;
    for (int c = lane; c < D_; c += 64) {
        float gv = g[c];
        d1 += gv * su[c];
        d2 += gv * sw[c];
        d3 += gv * s2[c];
    }
    #pragma unroll
    for (int off = 32; off; off >>= 1) {
        d1 += __shfl_xor(d1, off);
        d2 += __shfl_xor(d2, off);
        d3 += __shfl_xor(d3, off);
    }
    if (lane == 0) {
        Gu[row] = d1 + alpha[0];
        Gw[row] = d2;
        lg[row] = d3 + bk[0];
    }
}

// ---- k-softmax over T per batch, in place (lg -> normalized k) ----
__global__ __launch_bounds__(256) void ksoftmax_kernel(float* __restrict__ lg) {
    __shared__ float red[4];
    int b = blockIdx.x, tid = threadIdx.x;
    int wave = tid >> 6, lane = tid & 63;
    float* L = lg + (size_t)b * T_;
    float v0 = L[tid], v1 = L[tid + 256];
    float mx = fmaxf(v0, v1);
    #pragma unroll
    for (int off = 32; off; off >>= 1) mx = fmaxf(mx, __shfl_xor(mx, off));
    if (lane == 0) red[wave] = mx;
    __syncthreads();
    mx = fmaxf(fmaxf(red[0], red[1]), fmaxf(red[2], red[3]));
    __syncthreads();
    float e0 = expf(v0 - mx), e1 = expf(v1 - mx);
    float zs = e0 + e1;
    #pragma unroll
    for (int off = 32; off; off >>= 1) zs += __shfl_xor(zs, off);
    if (lane == 0) red[wave] = zs;
    __syncthreads();
    float invZ = 1.f / (red[0] + red[1] + red[2] + red[3]);
    L[tid] = e0 * invZ;
    L[tid + 256] = e1 * invZ;
}

// ---- partial c: part[(b*NCH+ch)*D+d] = sum_{t in chunk} k[b,t]*g[b,t,d] ----
__global__ __launch_bounds__(256) void csum_part(const float* __restrict__ gcn,
                                                 const float* __restrict__ k,
                                                 float* __restrict__ part) {
    __shared__ float kv[TCH];
    int d = blockIdx.x * 256 + threadIdx.x;
    int ch = blockIdx.y, b = blockIdx.z;
    if (threadIdx.x < TCH) kv[threadIdx.x] = k[(size_t)b * T_ + ch * TCH + threadIdx.x];
    __syncthreads();
    const float* gb = gcn + ((size_t)b * T_ + ch * TCH) * D_ + d;
    float acc = 0.f;
    #pragma unroll 4
    for (int i = 0; i < TCH; i++) acc += kv[i] * gb[(size_t)i * D_];
    part[((size_t)b * NCH + ch) * D_ + d] = acc;
}

// ---- reduce partials: c[b,d] = sum_ch part ----
__global__ __launch_bounds__(256) void csum_reduce(const float* __restrict__ part,
                                                   float* __restrict__ cbuf) {
    int d = blockIdx.x * 256 + threadIdx.x;
    int b = blockIdx.y;
    float acc = 0.f;
    #pragma unroll
    for (int ch = 0; ch < NCH; ch++) acc += part[((size_t)b * NCH + ch) * D_ + d];
    cbuf[(size_t)b * D_ + d] = acc;
}

// ---------------- split f32 -> hi/lo bf16 interleaved along last dim ----------------
__global__ __launch_bounds__(256) void split_kernel(const float* __restrict__ in,
                                                    short* __restrict__ out, size_t n4) {
    size_t i = (size_t)blockIdx.x * 256 + threadIdx.x;
    size_t stride = (size_t)gridDim.x * 256;
    for (; i < n4; i += stride) {
        f32x4 v = ((const f32x4*)in)[i];
        short8 o;
        #pragma unroll
        for (int j = 0; j < 4; j++) {
            short hi = bf16_of(v[j]);
            float r = v[j] - f32_of(hi);
            o[2 * j] = hi;
            o[2 * j + 1] = bf16_of(r);
        }
        ((short8*)out)[i] = o;
    }
}

// ---------------- out[z][c][r] = bf16(in[z][r][c]) ; R,C multiples of 32 ----------------
__global__ __launch_bounds__(256) void transpose_kernel(const float* __restrict__ in, size_t sIn,
                                                        short* __restrict__ out, size_t sOut,
                                                        int R, int C) {
    __shared__ float tile[32][33];
    int z = blockIdx.z;
    in += (size_t)z * sIn;
    out += (size_t)z * sOut;
    int c0 = blockIdx.x * 32, r0 = blockIdx.y * 32;
    int tx = threadIdx.x & 31, ty = threadIdx.x >> 5;
    #pragma unroll
    for (int i = 0; i < 4; i++) {
        int r = ty + i * 8;
        tile[r][tx] = in[(size_t)(r0 + r) * C + c0 + tx];
    }
    __syncthreads();
    #pragma unroll
    for (int i = 0; i < 4; i++) {
        int c = ty + i * 8;
        out[(size_t)(c0 + c) * R + r0 + tx] = bf16_of(tile[tx][c]);
    }
}

// ================= MFMA NT bf16 GEMM: C[m,n] = sum_k A[m,k]*Bt[n,k] =================
// 128x128 tile, 4 waves (2x2 of 64x64), 16x16x32 bf16 MFMA, f32 accum.
// MODE 0: f32 store | 1: f32 + Gu[row]+Gw[col] | 2: bf16 store
// MODE 3: f32 (acc+bV[col])*gate[z*D+col]      | 4: hi/lo split bf16 store (ldout=2N)
template <int MODE>
__global__ __launch_bounds__(256) void gemm_nt(
        const short* __restrict__ A, size_t sAz,
        const short* __restrict__ Bt, size_t sBz,
        int K, int ldout,
        float* __restrict__ Cf, short* __restrict__ Cb, size_t sCz,
        const float* __restrict__ e1, const float* __restrict__ e2) {
    __shared__ __align__(16) short As[128][72];
    __shared__ __align__(16) short Bs[128][72];
    int z = blockIdx.z;
    A += (size_t)z * sAz;
    Bt += (size_t)z * sBz;
    int t = threadIdx.x;
    int lane = t & 63, wave = t >> 6;
    int wr = wave >> 1, wc = wave & 1;
    size_t rowBase = (size_t)blockIdx.x * 128;
    size_t colBase = (size_t)blockIdx.y * 128;
    f32x4 acc[4][4] = {};
    int lrow = t >> 3;          // 0..31
    int lcol = (t & 7) * 8;     // 0..56
    for (int kb = 0; kb < K; kb += 64) {
        #pragma unroll
        for (int p = 0; p < 4; p++) {
            int r = p * 32 + lrow;
            *(short8*)(&As[r][lcol]) = *(const short8*)(&A[(rowBase + r) * (size_t)K + kb + lcol]);
            *(short8*)(&Bs[r][lcol]) = *(const short8*)(&Bt[(colBase + r) * (size_t)K + kb + lcol]);
        }
        __syncthreads();
        #pragma unroll
        for (int kk = 0; kk < 64; kk += 32) {
            int ko = kk + (lane >> 4) * 8;
            short8 af[4], bfr[4];
            #pragma unroll
            for (int i = 0; i < 4; i++)
                af[i] = *(const short8*)(&As[wr * 64 + i * 16 + (lane & 15)][ko]);
            #pragma unroll
            for (int j = 0; j < 4; j++)
                bfr[j] = *(const short8*)(&Bs[wc * 64 + j * 16 + (lane & 15)][ko]);
            #pragma unroll
            for (int i = 0; i < 4; i++)
                #pragma unroll
                for (int j = 0; j < 4; j++)
                    acc[i][j] = __builtin_amdgcn_mfma_f32_16x16x32_bf16(af[i], bfr[j], acc[i][j], 0, 0, 0);
        }
        __syncthreads();
    }
    #pragma unroll
    for (int i = 0; i < 4; i++) {
        #pragma unroll
        for (int j = 0; j < 4; j++) {
            #pragma unroll
            for (int r = 0; r < 4; r++) {
                size_t row = rowBase + wr * 64 + i * 16 + (lane >> 4) * 4 + r;
                size_t col = colBase + wc * 64 + j * 16 + (lane & 15);
                float v = acc[i][j][r];
                if (MODE == 0) {
                    Cf[z * sCz + row * ldout + col] = v;
                } else if (MODE == 1) {
                    Cf[z * sCz + row * ldout + col] = v + e1[z * T_ + row] + e2[z * T_ + col];
                } else if (MODE == 2) {
                    Cb[z * sCz + row * ldout + col] = bf16_of(v);
                } else if (MODE == 3) {
                    Cf[z * sCz + row * ldout + col] = (v + e1[col]) * e2[(size_t)z * D_ + col];
                } else {
                    short hi = bf16_of(v);
                    float rr = v - f32_of(hi);
                    short2v o;
                    o[0] = hi;
                    o[1] = bf16_of(rr);
                    *(short2v*)(&Cb[row * (size_t)ldout + 2 * col]) = o;
                }
            }
        }
    }
}

// ---------------- per-row: att out (f32) + probs out (bf16) ----------------
__global__ __launch_bounds__(64) void softmax_att(const float* __restrict__ S,
                                                  short* __restrict__ probs,
                                                  float* __restrict__ att) {
    const float SCALE = 0.03125f;  // 1/sqrt(1024)
    int t = blockIdx.x, z = blockIdx.y, lane = threadIdx.x;
    const float* row = S + ((size_t)z * T_ + t) * T_;
    short* prow = probs + ((size_t)z * T_ + t) * T_;
    float v[8];
    float mx = -1e30f;
    #pragma unroll
    for (int k = 0; k < 8; k++) {
        v[k] = row[lane + k * 64];
        mx = fmaxf(mx, v[k]);
    }
    #pragma unroll
    for (int off = 32; off; off >>= 1) mx = fmaxf(mx, __shfl_xor(mx, off));
    float z1 = 0.f, z2 = 0.f, dg = 0.f;
    #pragma unroll
    for (int k = 0; k < 8; k++) {
        float x = v[k] - mx;
        float e1 = expf(x);
        float e2 = expf(x * SCALE);
        z1 += e1;
        z2 += e2;
        if (lane + k * 64 == t) dg = e1;
        v[k] = e2;
    }
    #pragma unroll
    for (int off = 32; off; off >>= 1) {
        z1 += __shfl_xor(z1, off);
        z2 += __shfl_xor(z2, off);
        dg += __shfl_xor(dg, off);
    }
    float inv2 = 1.f / z2;
    #pragma unroll
    for (int k = 0; k < 8; k++) prow[lane + k * 64] = bf16_of(v[k] * inv2);
    if (lane == 0) att[z * T_ + t] = SCALE * (1.f - dg / z1);
}

// ---------------- masks passthrough (f32) ----------------
__global__ __launch_bounds__(256) void masks_kernel(const int* __restrict__ masks,
                                                    float* __restrict__ out_masks) {
    int i = blockIdx.x * 256 + threadIdx.x;
    if (i < B_ * T_) out_masks[i] = (float)masks[i];
}

extern "C" void kernel_launch(void* const* d_in, const int* in_sizes, int n_in,
                              void* d_out, int out_size, void* d_ws, size_t ws_size,
                              hipStream_t stream) {
    const float* gcn = (const float*)d_in[0];
    const int* subj_pos = (const int*)d_in[1];
    const int* masks = (const int*)d_in[3];
    const float* Wq = (const float*)d_in[4];
    const float* bq = (const float*)d_in[5];
    const float* Wc = (const float*)d_in[6];
    const float* bc = (const float*)d_in[7];
    const float* Wk = (const float*)d_in[8];
    const float* bk = (const float*)d_in[9];
    const float* Wm = (const float*)d_in[10];
    const float* bm = (const float*)d_in[11];
    const float* WK = (const float*)d_in[12];
    const float* bK = (const float*)d_in[13];
    const float* WQ = (const float*)d_in[14];
    const float* bQ = (const float*)d_in[15];
    const float* WV = (const float*)d_in[16];
    const float* bV = (const float*)d_in[17];

    float* out = (float*)d_out;

    // ---- workspace layout (bytes, 256-aligned chunks) ----
    char* p = (char*)d_ws;
    auto alloc = [&](size_t bytes) {
        char* r = p;
        p += (bytes + 255) & ~(size_t)255;
        return r;
    };
    float* subj = (float*)alloc(B_ * D_ * 4);
    float* qv   = (float*)alloc(B_ * D_ * 4);
    float* tv   = (float*)alloc(B_ * D_ * 4);
    float* cb   = (float*)alloc(B_ * D_ * 4);
    float* mb   = (float*)alloc(B_ * D_ * 4);
    float* u    = (float*)alloc(D_ * 4);
    float* w    = (float*)alloc(D_ * 4);
    float* alph = (float*)alloc(256);
    float* Gu   = (float*)alloc(B_ * T_ * 4);
    float* Gw   = (float*)alloc(B_ * T_ * 4);
    float* lg   = (float*)alloc(B_ * T_ * 4);
    float* part = (float*)alloc((size_t)B_ * NCH * D_ * 4);
    float* Pt   = (float*)alloc((size_t)D_ * D_ * 4);
    short* WKs  = (short*)alloc((size_t)D_ * 2 * D_ * 2);
    short* WQs  = (short*)alloc((size_t)D_ * 2 * D_ * 2);
    short* Pts  = (short*)alloc((size_t)D_ * 2 * D_ * 2);
    short* WVt  = (short*)alloc((size_t)D_ * D_ * 2);

    size_t fixedBytes = (size_t)(p - (char*)d_ws);
    // per-chunk bytes (nc batches): Gs + Ys + Gt + S + probs + Zs
    const size_t perBatch = (size_t)T_ * 2 * D_ * 2   // Gs
                          + (size_t)T_ * 2 * D_ * 2   // Ys
                          + (size_t)D_ * T_ * 2       // Gt
                          + (size_t)T_ * T_ * 4       // S
                          + (size_t)T_ * T_ * 2       // probs
                          + (size_t)T_ * D_ * 2;      // Zs
    int nc = 64;
    while (nc > 1 && fixedBytes + (size_t)nc * perBatch + 4096 > ws_size) nc >>= 1;

    short* Gs_c    = (short*)alloc((size_t)nc * T_ * 2 * D_ * 2);
    short* Ys_c    = (short*)alloc((size_t)nc * T_ * 2 * D_ * 2);
    short* Gt_c    = (short*)alloc((size_t)nc * D_ * T_ * 2);
    float* S_c     = (float*)alloc((size_t)nc * T_ * T_ * 4);
    short* probs_c = (short*)alloc((size_t)nc * T_ * T_ * 2);
    short* Zs_c    = (short*)alloc((size_t)nc * T_ * D_ * 2);

    // ---- small path: gate m and pooled vectors (parallel c-attention) ----
    pool_kernel<<<dim3(D_ / 256, B_), 256, 0, stream>>>(gcn, subj_pos, subj);
    mv_q<<<dim3(D_ / 256, B_), 256, 0, stream>>>(subj, Wq, bq, qv);
    mv_t<<<dim3(D_ / 256, B_), 256, 0, stream>>>(qv, Wc, bc, tv);
    vecs_kernel<<<D_ / 4, 256, 0, stream>>>(WK, WQ, bK, bQ, u, w, alph);
    att_dots<<<B_ * T_ / 4, 256, 0, stream>>>(gcn, u, w, tv, Wk, alph, bk, Gu, Gw, lg);
    ksoftmax_kernel<<<B_, 256, 0, stream>>>(lg);
    csum_part<<<dim3(D_ / 256, NCH, B_), 256, 0, stream>>>(gcn, lg, part);
    csum_reduce<<<dim3(D_ / 256, B_), 256, 0, stream>>>(part, cb);
    mv_m<<<dim3(D_ / 256, B_), 256, 0, stream>>>(cb, subj, Wm, bm, mb);

    // ---- factorization precompute (split precision) ----
    split_kernel<<<1024, 256, 0, stream>>>(WK, WKs, (size_t)D_ * D_ / 4);
    split_kernel<<<1024, 256, 0, stream>>>(WQ, WQs, (size_t)D_ * D_ / 4);
    // Pt[c,a] = sum_k WQ[c,k]*WK[a,k]  (= P[a,c])
    gemm_nt<0><<<dim3(8, 8, 1), 256, 0, stream>>>(WQs, 0, WKs, 0, 2 * D_, D_,
                                                  Pt, nullptr, 0, nullptr, nullptr);
    split_kernel<<<1024, 256, 0, stream>>>(Pt, Pts, (size_t)D_ * D_ / 4);
    // WVt[d,k] = WV[k,d]
    transpose_kernel<<<dim3(32, 32, 1), 256, 0, stream>>>(WV, 0, WVt, 0, D_, D_);

    // ---- chunked attention ----
    for (int b0 = 0; b0 < B_; b0 += nc) {
        const float* Gc = gcn + (size_t)b0 * T_ * D_;
        // Gs = split(G), Gt = bf16(G^T)
        split_kernel<<<2048, 256, 0, stream>>>(Gc, Gs_c, (size_t)nc * T_ * D_ / 4);
        transpose_kernel<<<dim3(D_ / 32, T_ / 32, nc), 256, 0, stream>>>(
            Gc, (size_t)T_ * D_, Gt_c, (size_t)D_ * T_, T_, D_);
        // Y = G@P (split in, split-store out): A=Gs [nc*T, 2D], Bt=Pts [D, 2D]
        gemm_nt<4><<<dim3(nc * T_ / 128, D_ / 128, 1), 256, 0, stream>>>(
            Gs_c, 0, Pts, 0, 2 * D_, 2 * D_, nullptr, Ys_c, 0, nullptr, nullptr);
        // S = Y@G^T + Gu + Gw : A=Ys(z), Bt=Gs(z), K=2D
        gemm_nt<1><<<dim3(T_ / 128, T_ / 128, nc), 256, 0, stream>>>(
            Ys_c, (size_t)T_ * 2 * D_, Gs_c, (size_t)T_ * 2 * D_, 2 * D_, T_,
            S_c, nullptr, (size_t)T_ * T_, Gu + (size_t)b0 * T_, Gw + (size_t)b0 * T_);
        // softmax: att (f32) + probs (bf16)
        softmax_att<<<dim3(T_, nc), 64, 0, stream>>>(S_c, probs_c, out + OUT3_OFF + (size_t)b0 * T_);
        // Z = probs@G : A=probs(z) [T,T], Bt=Gt(z) [D,T], K=T -> bf16
        gemm_nt<2><<<dim3(T_ / 128, D_ / 128, nc), 256, 0, stream>>>(
            probs_c, (size_t)T_ * T_, Gt_c, (size_t)D_ * T_, T_, D_,
            nullptr, Zs_c, (size_t)T_ * D_, nullptr, nullptr);
        // out0 = (Z@WV + bV) * m : A=Zs(z) [T,D], Bt=WVt [D,D], K=D
        gemm_nt<3><<<dim3(T_ / 128, D_ / 128, nc), 256, 0, stream>>>(
            Zs_c, (size_t)T_ * D_, WVt, 0, D_, D_,
            out + OUT0_OFF + (size_t)b0 * T_ * D_, nullptr, (size_t)T_ * D_,
            bV, mb + (size_t)b0 * D_);
    }

    // ---- passthroughs ----
    hipMemcpyAsync(out + OUT2_OFF, gcn, (size_t)B_ * T_ * D_ * sizeof(float),
                   hipMemcpyDeviceToDevice, stream);
    masks_kernel<<<(B_ * T_ + 255) / 256, 256, 0, stream>>>(masks, out + OUT1_OFF);
}